// Round 9
// baseline (21986.000 us; speedup 1.0000x reference)
//
#include <hip/hip_runtime.h>
#include <hip/hip_bf16.h>
#include <stdint.h>

// LSTM persistent kernel, round 9: r8 (self-signaling h, tag-in-LSB) + a VALU
// "heater" chain inside the poll spin. Purpose: DVFS probe. Three sync designs
// (r2/r6/r8) all measure 10.2-10.8 us/step regardless of topology/hop count,
// ~4x the full-clock cycle estimate -> suspect the SMU holds a low engine
// clock because the kernel looks ~97% idle (VALUBusy 2.5%). The heater makes
// every spinning lane execute 48 dependent v_fma_f32 between polls (~80ns,
// negligible detect-latency cost) so per-CU activity rises during the
// dominant wait phase. Everything else is byte-identical to r8.
// T=2048, B=64, I=512, H=512.
// 64 blocks = 2 batch-groups x 32 col-groups; block owns 32 batches x 16 h-cols.

#define T_STEPS 2048
#define BATCH   64
#define IDIM    512
#define HDIM    512

typedef __attribute__((ext_vector_type(8))) short  vshort8;
typedef __attribute__((ext_vector_type(4))) float  vfloat4;

__device__ __forceinline__ unsigned short f2bf(float f) {
  unsigned int u = __builtin_bit_cast(unsigned int, f);
  u += 0x7fffu + ((u >> 16) & 1u);          // round-to-nearest-even
  return (unsigned short)(u >> 16);
}

__device__ __forceinline__ vfloat4 mfma_bf16(vshort8 a, vshort8 b, vfloat4 c) {
  asm("v_mfma_f32_16x16x32_bf16 %0, %1, %2, %0" : "+v"(c) : "v"(a), "v"(b));
  return c;
}

__device__ __forceinline__ float sigmoid_(float x) {
  return 1.0f / (1.0f + __expf(-x));
}
__device__ __forceinline__ float tanh_(float x) {
  float ax = fabsf(x);
  float t  = __expf(-2.0f * ax);
  float y  = (1.0f - t) / (1.0f + t);
  return x < 0.0f ? -y : y;
}

// zero flags region (unused, kept for layout) + hbuf: 34816 uints.
// Zeroed hbuf has LSB=0 everywhere -> can never match the first generation
// tag of each buffer (gen sequence 1,1,0,0,1,1,...).
__global__ void lstm_zero_ws(unsigned int* ws) {
  const int i = blockIdx.x * 256 + threadIdx.x;
  if (i < 34816) ws[i] = 0u;
}

__global__ __launch_bounds__(256, 1)
void lstm_persistent(const float* __restrict__ word_seq,
                     const float* __restrict__ w_ih,
                     const float* __restrict__ w_hh,
                     const float* __restrict__ b_ih,
                     const float* __restrict__ b_hh,
                     float* __restrict__ out,
                     unsigned short* __restrict__ hbuf) {
  // x tile: 32 rows x 512 cols bf16 (+8 pad). red = cross-wave K-reduction.
  __shared__ unsigned short x_s[32][520];
  __shared__ float red[4][2][4][16][20];   // [wave][rowtile][gate][dcol][drow+pad]

  const int tid  = threadIdx.x;
  const int blk  = blockIdx.x;
  const int bg   = blk >> 5;   // batch group: batches [bg*32, bg*32+32)
  const int cg   = blk & 31;   // col group:   h-cols  [cg*16, cg*16+16)
  const int wv   = tid >> 6;   // wave 0..3 (K-split)
  const int lane = tid & 63;
  const int mrow = lane & 15;  // A-row / B-col lane index
  const int g4   = lane >> 4;  // k-group 0..3

  // ------- weight B-fragments (bf16) into registers, once -------
  // B[k][n] = W[gc(n)][k]; k = wv*128 + kk*32 + g4*8 + j (same k-hat as A frags)
  vshort8 bw[2][4][4];
#pragma unroll
  for (int p = 0; p < 2; ++p) {
    const float* W = p ? w_hh : w_ih;
#pragma unroll
    for (int n = 0; n < 4; ++n) {
      const int gc = n * 512 + cg * 16 + mrow;
#pragma unroll
      for (int kk = 0; kk < 4; ++kk) {
        const int k0 = wv * 128 + kk * 32 + g4 * 8;
        const float* src = W + (size_t)gc * 512 + k0;
        vshort8 fr;
#pragma unroll
        for (int j = 0; j < 8; ++j) fr[j] = (short)f2bf(src[j]);
        bw[p][n][kk] = fr;
      }
    }
  }

  // ------- per-thread output ownership: 2 adjacent h-cols of one batch row -------
  const int orow = tid >> 3;           // batch-local row 0..31
  const int om   = (tid & 7) * 2;      // even local col in n-tile, 0..14
  const int ort  = orow >> 4;          // row tile
  const int odr  = orow & 15;          // d-row within tile

  float bsum[4][2];
#pragma unroll
  for (int n = 0; n < 4; ++n)
#pragma unroll
    for (int e = 0; e < 2; ++e) {
      const int gc = n * 512 + cg * 16 + om + e;
      bsum[n][e] = b_ih[gc] + b_hh[gc];
    }

  float cst[2]   = {0.0f, 0.0f};
  float hlast[2] = {0.0f, 0.0f};

  // heater state (never consumed; asm volatile keeps it un-eliminable)
  float jh0 = 1.000001f;
  const float jh1 = 0.9999991f;

  // ------- stage x_0 (wave-local k-window: cols [wv*128, wv*128+128)) -------
#pragma unroll
  for (int it = 0; it < 16; ++it) {
    const int idx = it * 64 + lane;          // 0..1023
    const int row = idx >> 5;                // 0..31
    const int c4  = idx & 31;                // float4 index within window
    const int col = wv * 128 + c4 * 4;
    const float4 v = *(const float4*)(word_seq + ((size_t)bg * 32 + row) * 512 + col);
    ushort4 us;
    us.x = f2bf(v.x); us.y = f2bf(v.y); us.z = f2bf(v.z); us.w = f2bf(v.w);
    *(ushort4*)&x_s[row][col] = us;
  }

  // ===================== main sequential loop =====================
#pragma unroll 1
  for (int t = 0; t < T_STEPS; ++t) {
    // ---- x-part MFMA from LDS (wave-own k-window)
    vfloat4 acc[2][4];
#pragma unroll
    for (int r = 0; r < 2; ++r)
#pragma unroll
      for (int n = 0; n < 4; ++n) acc[r][n] = (vfloat4)0.0f;

#pragma unroll
    for (int kk = 0; kk < 4; ++kk) {
      const int kb = wv * 128 + kk * 32 + g4 * 8;
      const vshort8 a0 = *(const vshort8*)&x_s[mrow][kb];
      const vshort8 a1 = *(const vshort8*)&x_s[16 + mrow][kb];
#pragma unroll
      for (int n = 0; n < 4; ++n) {
        acc[0][n] = mfma_bf16(a0, bw[0][n][kk], acc[0][n]);
        acc[1][n] = mfma_bf16(a1, bw[0][n][kk], acc[1][n]);
      }
    }

    if (t > 0) {
      // ---- poll-fused h_{t-1} load: retry until every packed word carries
      //      the expected generation tag in BOTH bf16 LSBs.
      const unsigned gr = (((unsigned)(t - 1) >> 1) & 1u) ^ 1u;  // expected gen
      const unsigned short* hbR =
          hbuf + ((size_t)((t - 1) & 1) * BATCH + bg * 32) * 512;
      vshort8 hfr[2][4];
      unsigned bad = 1u;
      int guard = 0;
      while (__ballot(bad != 0u) != 0ull) {
        if (bad) {
          bad = 0u;
#pragma unroll
          for (int r = 0; r < 2; ++r)
#pragma unroll
            for (int kk = 0; kk < 4; ++kk) {
              const int kb = wv * 128 + kk * 32 + g4 * 8;
              const unsigned long long* p =
                  (const unsigned long long*)(hbR + (r * 16 + mrow) * 512 + kb);
              union { struct { unsigned long long lo, hi; } q; vshort8 v; } u;
              u.q.lo = __hip_atomic_load(p,     __ATOMIC_RELAXED,
                                         __HIP_MEMORY_SCOPE_AGENT);
              u.q.hi = __hip_atomic_load(p + 1, __ATOMIC_RELAXED,
                                         __HIP_MEMORY_SCOPE_AGENT);
              hfr[r][kk] = u.v;
              const unsigned w0 = (unsigned)u.q.lo;
              const unsigned w1 = (unsigned)(u.q.lo >> 32);
              const unsigned w2 = (unsigned)u.q.hi;
              const unsigned w3 = (unsigned)(u.q.hi >> 32);
              // word valid iff (w&1)==gr and ((w>>16)&1)==gr
              bad |= (((w0 ^ (w0 >> 16)) & 1u) | ((w0 & 1u) ^ gr));
              bad |= (((w1 ^ (w1 >> 16)) & 1u) | ((w1 & 1u) ^ gr));
              bad |= (((w2 ^ (w2 >> 16)) & 1u) | ((w2 & 1u) ^ gr));
              bad |= (((w3 ^ (w3 >> 16)) & 1u) | ((w3 & 1u) ^ gr));
            }
        }
        // ---- DVFS heater: 48 dependent FMAs (~80ns) so the CU looks busy
        //      while we wait; un-eliminable, never consumed.
#pragma unroll
        for (int hj = 0; hj < 48; ++hj)
          asm volatile("v_fma_f32 %0, %0, %1, %0" : "+v"(jh0) : "v"(jh1));
        if (++guard > (1 << 14)) break;   // failsafe: wrong answer beats a hang
      }
      asm volatile("" ::: "memory");

      // ---- h-part MFMA (hfr delivered by the successful poll iteration)
#pragma unroll
      for (int kk = 0; kk < 4; ++kk)
#pragma unroll
        for (int n = 0; n < 4; ++n) {
          acc[0][n] = mfma_bf16(hfr[0][kk], bw[1][n][kk], acc[0][n]);
          acc[1][n] = mfma_bf16(hfr[1][kk], bw[1][n][kk], acc[1][n]);
        }
    }

    // MFMA->VALU/DS hazard guard (inline-asm MFMA bypasses hazard recognizer)
    asm volatile("s_nop 7\n\ts_nop 7" ::: "memory");

    // ---- per-wave partials; D layout: col=lane&15, row=(lane>>4)*4+reg
#pragma unroll
    for (int r = 0; r < 2; ++r)
#pragma unroll
      for (int n = 0; n < 4; ++n)
        *(vfloat4*)&red[wv][r][n][mrow][g4 * 4] = acc[r][n];
    __syncthreads();                                     // sync 1

    // ---- reduce across waves + bias
    float gate[4][2];
#pragma unroll
    for (int n = 0; n < 4; ++n) {
      float s0 = bsum[n][0], s1 = bsum[n][1];
#pragma unroll
      for (int w2 = 0; w2 < 4; ++w2) {
        s0 += red[w2][ort][n][om][odr];
        s1 += red[w2][ort][n][om + 1][odr];
      }
      gate[n][0] = s0; gate[n][1] = s1;
    }
    __syncthreads();   // sync 2: red reads complete before next-iter red writes

    // ---- activations, state update
    float hv[2];
#pragma unroll
    for (int e = 0; e < 2; ++e) {
      const float ig = sigmoid_(gate[0][e]);
      const float fg = sigmoid_(gate[1][e]);
      const float gg = tanh_(gate[2][e]);
      const float og = sigmoid_(gate[3][e]);
      cst[e] = fg * cst[e] + ig * gg;
      hv[e]  = og * tanh_(cst[e]);
    }
    hlast[0] = hv[0]; hlast[1] = hv[1];

    // ---- publish h with generation tag in each bf16 LSB (<=1 ulp distortion)
    {
      const unsigned gw = (((unsigned)t >> 1) & 1u) ^ 1u;
      unsigned u0 = f2bf(hv[0]);  u0 += ((u0 & 1u) ^ gw);
      unsigned u1 = f2bf(hv[1]);  u1 += ((u1 & 1u) ^ gw);
      const unsigned packed = (u0 & 0xffffu) | (u1 << 16);
      unsigned int* hbW = (unsigned int*)(hbuf +
          ((size_t)(t & 1) * BATCH + bg * 32) * 512 + orow * 512 + cg * 16 + om);
      __hip_atomic_store(hbW, packed, __ATOMIC_RELAXED, __HIP_MEMORY_SCOPE_AGENT);

      float2 h2; h2.x = hv[0]; h2.y = hv[1];
      *(float2*)&out[((size_t)t * BATCH + bg * 32 + orow) * 512 + cg * 16 + om] = h2;
    }

    // ---- stage x_{t+1} (wave-local slice); overlaps peers' publish latency
    if (t + 1 < T_STEPS) {
#pragma unroll
      for (int it = 0; it < 16; ++it) {
        const int idx = it * 64 + lane;
        const int row = idx >> 5;
        const int c4  = idx & 31;
        const int col = wv * 128 + c4 * 4;
        const float4 v = *(const float4*)(word_seq +
            ((size_t)(t + 1) * BATCH + bg * 32 + row) * 512 + col);
        ushort4 us;
        us.x = f2bf(v.x); us.y = f2bf(v.y); us.z = f2bf(v.z); us.w = f2bf(v.w);
        *(ushort4*)&x_s[row][col] = us;
      }
    }
  }

  // ------- tails: final h and c (fp32) -------
  {
    const size_t tail = (size_t)T_STEPS * BATCH * HDIM;
    const size_t gb   = (size_t)bg * 32 + orow;
    const int    col  = cg * 16 + om;
    float2 h2; h2.x = hlast[0]; h2.y = hlast[1];
    float2 c2; c2.x = cst[0];   c2.y = cst[1];
    *(float2*)&out[tail + gb * 512 + col] = h2;
    *(float2*)&out[tail + (size_t)BATCH * HDIM + gb * 512 + col] = c2;
  }
}

extern "C" void kernel_launch(void* const* d_in, const int* in_sizes, int n_in,
                              void* d_out, int out_size, void* d_ws, size_t ws_size,
                              hipStream_t stream) {
  (void)in_sizes; (void)n_in; (void)out_size; (void)ws_size;
  const float* word_seq = (const float*)d_in[0];
  const float* w_ih     = (const float*)d_in[1];
  const float* w_hh     = (const float*)d_in[2];
  const float* b_ih     = (const float*)d_in[3];
  const float* b_hh     = (const float*)d_in[4];
  float* out = (float*)d_out;

  unsigned short* hbuf = (unsigned short*)((char*)d_ws + 8192);

  lstm_zero_ws<<<136, 256, 0, stream>>>((unsigned int*)d_ws);
  lstm_persistent<<<64, 256, 0, stream>>>(word_seq, w_ih, w_hh, b_ih, b_hh,
                                          out, hbuf);
}

// Round 10
// 21985.815 us; speedup vs baseline: 1.0000x; 1.0000x over previous
//
#include <hip/hip_runtime.h>
#include <hip/hip_bf16.h>
#include <stdint.h>

// LSTM persistent kernel, round 10: r8 (self-signaling h via LSB generation
// tags) + a DEDICATED HEATER WAVE (5th wave per block). DVFS probe, done
// right this time: r9 proved the poll spin exits almost immediately (heater
// in the spin raised VALUBusy only +0.15%), so the 10.5 us/step is
// block-local serial work. That chain is ~6000 cycles -> effective clock
// ~570 MHz: the SMU is holding the bottom DPM state because the kernel looks
// ~97% idle. The heater wave issues 1600 independent-chain v_fma_f32 per
// timestep (~3200 cyc: 1.3us @2.4GHz, 5.3us @600MHz -- always shorter than
// the step, so it NEVER extends the period; it only raises per-CU activity),
// then meets the same 2 barriers/iteration. Everything else byte-identical
// to r8. T=2048, B=64, I=512, H=512.
// 64 blocks = 2 batch-groups x 32 col-groups; block owns 32 batches x 16 h-cols.

#define T_STEPS 2048
#define BATCH   64
#define IDIM    512
#define HDIM    512

typedef __attribute__((ext_vector_type(8))) short  vshort8;
typedef __attribute__((ext_vector_type(4))) float  vfloat4;

__device__ __forceinline__ unsigned short f2bf(float f) {
  unsigned int u = __builtin_bit_cast(unsigned int, f);
  u += 0x7fffu + ((u >> 16) & 1u);          // round-to-nearest-even
  return (unsigned short)(u >> 16);
}

__device__ __forceinline__ vfloat4 mfma_bf16(vshort8 a, vshort8 b, vfloat4 c) {
  asm("v_mfma_f32_16x16x32_bf16 %0, %1, %2, %0" : "+v"(c) : "v"(a), "v"(b));
  return c;
}

__device__ __forceinline__ float sigmoid_(float x) {
  return 1.0f / (1.0f + __expf(-x));
}
__device__ __forceinline__ float tanh_(float x) {
  float ax = fabsf(x);
  float t  = __expf(-2.0f * ax);
  float y  = (1.0f - t) / (1.0f + t);
  return x < 0.0f ? -y : y;
}

// zero flags region (unused, kept for layout) + hbuf: 34816 uints.
// Zeroed hbuf has LSB=0 everywhere -> can never match the first generation
// tag of each buffer (gen sequence 1,1,0,0,1,1,...).
__global__ void lstm_zero_ws(unsigned int* ws) {
  const int i = blockIdx.x * 256 + threadIdx.x;
  if (i < 34816) ws[i] = 0u;
}

__global__ __launch_bounds__(320, 1)
void lstm_persistent(const float* __restrict__ word_seq,
                     const float* __restrict__ w_ih,
                     const float* __restrict__ w_hh,
                     const float* __restrict__ b_ih,
                     const float* __restrict__ b_hh,
                     float* __restrict__ out,
                     unsigned short* __restrict__ hbuf) {
  // x tile: 32 rows x 512 cols bf16 (+8 pad). red = cross-wave K-reduction.
  __shared__ unsigned short x_s[32][520];
  __shared__ float red[4][2][4][16][20];   // [wave][rowtile][gate][dcol][drow+pad]

  const int tid  = threadIdx.x;
  const int blk  = blockIdx.x;
  const int bg   = blk >> 5;   // batch group: batches [bg*32, bg*32+32)
  const int cg   = blk & 31;   // col group:   h-cols  [cg*16, cg*16+16)
  const int wv   = tid >> 6;   // wave 0..3 (K-split); wave 4 = heater
  const int lane = tid & 63;
  const int mrow = lane & 15;  // A-row / B-col lane index
  const int g4   = lane >> 4;  // k-group 0..3

  // ===================== heater wave (tid 256..319) =====================
  // Pure VALU duty cycle so the SMU sees a busy CU. 1600 FMAs/step via 4
  // independent chains (issue-limited ~2 cyc/FMA). Matches the compute
  // waves' 2 barriers per iteration exactly, then terminates (no barriers
  // exist after the main loop, so early wave exit is safe).
  if (tid >= 256) {
    float a0 = 1.000001f, a1 = 1.000002f, a2 = 0.999999f, a3 = 0.999998f;
    const float m = 0.99999988f;
#pragma unroll 1
    for (int t = 0; t < T_STEPS; ++t) {
#pragma unroll 1
      for (int i = 0; i < 100; ++i) {
        asm volatile(
          "v_fma_f32 %0, %0, %4, %0\n\t" "v_fma_f32 %1, %1, %4, %1\n\t"
          "v_fma_f32 %2, %2, %4, %2\n\t" "v_fma_f32 %3, %3, %4, %3\n\t"
          "v_fma_f32 %0, %0, %4, %0\n\t" "v_fma_f32 %1, %1, %4, %1\n\t"
          "v_fma_f32 %2, %2, %4, %2\n\t" "v_fma_f32 %3, %3, %4, %3\n\t"
          "v_fma_f32 %0, %0, %4, %0\n\t" "v_fma_f32 %1, %1, %4, %1\n\t"
          "v_fma_f32 %2, %2, %4, %2\n\t" "v_fma_f32 %3, %3, %4, %3\n\t"
          "v_fma_f32 %0, %0, %4, %0\n\t" "v_fma_f32 %1, %1, %4, %1\n\t"
          "v_fma_f32 %2, %2, %4, %2\n\t" "v_fma_f32 %3, %3, %4, %3"
          : "+v"(a0), "+v"(a1), "+v"(a2), "+v"(a3) : "v"(m));
      }
      __syncthreads();                     // matches compute sync 1
      __syncthreads();                     // matches compute sync 2
    }
    return;
  }

  // ===================== compute waves (tid 0..255): r8 verbatim ==========

  // ------- weight B-fragments (bf16) into registers, once -------
  // B[k][n] = W[gc(n)][k]; k = wv*128 + kk*32 + g4*8 + j (same k-hat as A frags)
  vshort8 bw[2][4][4];
#pragma unroll
  for (int p = 0; p < 2; ++p) {
    const float* W = p ? w_hh : w_ih;
#pragma unroll
    for (int n = 0; n < 4; ++n) {
      const int gc = n * 512 + cg * 16 + mrow;
#pragma unroll
      for (int kk = 0; kk < 4; ++kk) {
        const int k0 = wv * 128 + kk * 32 + g4 * 8;
        const float* src = W + (size_t)gc * 512 + k0;
        vshort8 fr;
#pragma unroll
        for (int j = 0; j < 8; ++j) fr[j] = (short)f2bf(src[j]);
        bw[p][n][kk] = fr;
      }
    }
  }

  // ------- per-thread output ownership: 2 adjacent h-cols of one batch row -------
  const int orow = tid >> 3;           // batch-local row 0..31
  const int om   = (tid & 7) * 2;      // even local col in n-tile, 0..14
  const int ort  = orow >> 4;          // row tile
  const int odr  = orow & 15;          // d-row within tile

  float bsum[4][2];
#pragma unroll
  for (int n = 0; n < 4; ++n)
#pragma unroll
    for (int e = 0; e < 2; ++e) {
      const int gc = n * 512 + cg * 16 + om + e;
      bsum[n][e] = b_ih[gc] + b_hh[gc];
    }

  float cst[2]   = {0.0f, 0.0f};
  float hlast[2] = {0.0f, 0.0f};

  // ------- stage x_0 (wave-local k-window: cols [wv*128, wv*128+128)) -------
#pragma unroll
  for (int it = 0; it < 16; ++it) {
    const int idx = it * 64 + lane;          // 0..1023
    const int row = idx >> 5;                // 0..31
    const int c4  = idx & 31;                // float4 index within window
    const int col = wv * 128 + c4 * 4;
    const float4 v = *(const float4*)(word_seq + ((size_t)bg * 32 + row) * 512 + col);
    ushort4 us;
    us.x = f2bf(v.x); us.y = f2bf(v.y); us.z = f2bf(v.z); us.w = f2bf(v.w);
    *(ushort4*)&x_s[row][col] = us;
  }

  // ===================== main sequential loop =====================
#pragma unroll 1
  for (int t = 0; t < T_STEPS; ++t) {
    // ---- x-part MFMA from LDS (wave-own k-window)
    vfloat4 acc[2][4];
#pragma unroll
    for (int r = 0; r < 2; ++r)
#pragma unroll
      for (int n = 0; n < 4; ++n) acc[r][n] = (vfloat4)0.0f;

#pragma unroll
    for (int kk = 0; kk < 4; ++kk) {
      const int kb = wv * 128 + kk * 32 + g4 * 8;
      const vshort8 a0 = *(const vshort8*)&x_s[mrow][kb];
      const vshort8 a1 = *(const vshort8*)&x_s[16 + mrow][kb];
#pragma unroll
      for (int n = 0; n < 4; ++n) {
        acc[0][n] = mfma_bf16(a0, bw[0][n][kk], acc[0][n]);
        acc[1][n] = mfma_bf16(a1, bw[0][n][kk], acc[1][n]);
      }
    }

    if (t > 0) {
      // ---- poll-fused h_{t-1} load: retry until every packed word carries
      //      the expected generation tag in BOTH bf16 LSBs.
      const unsigned gr = (((unsigned)(t - 1) >> 1) & 1u) ^ 1u;  // expected gen
      const unsigned short* hbR =
          hbuf + ((size_t)((t - 1) & 1) * BATCH + bg * 32) * 512;
      vshort8 hfr[2][4];
      unsigned bad = 1u;
      int guard = 0;
      while (__ballot(bad != 0u) != 0ull) {
        if (bad) {
          bad = 0u;
#pragma unroll
          for (int r = 0; r < 2; ++r)
#pragma unroll
            for (int kk = 0; kk < 4; ++kk) {
              const int kb = wv * 128 + kk * 32 + g4 * 8;
              const unsigned long long* p =
                  (const unsigned long long*)(hbR + (r * 16 + mrow) * 512 + kb);
              union { struct { unsigned long long lo, hi; } q; vshort8 v; } u;
              u.q.lo = __hip_atomic_load(p,     __ATOMIC_RELAXED,
                                         __HIP_MEMORY_SCOPE_AGENT);
              u.q.hi = __hip_atomic_load(p + 1, __ATOMIC_RELAXED,
                                         __HIP_MEMORY_SCOPE_AGENT);
              hfr[r][kk] = u.v;
              const unsigned w0 = (unsigned)u.q.lo;
              const unsigned w1 = (unsigned)(u.q.lo >> 32);
              const unsigned w2 = (unsigned)u.q.hi;
              const unsigned w3 = (unsigned)(u.q.hi >> 32);
              // word valid iff (w&1)==gr and ((w>>16)&1)==gr
              bad |= (((w0 ^ (w0 >> 16)) & 1u) | ((w0 & 1u) ^ gr));
              bad |= (((w1 ^ (w1 >> 16)) & 1u) | ((w1 & 1u) ^ gr));
              bad |= (((w2 ^ (w2 >> 16)) & 1u) | ((w2 & 1u) ^ gr));
              bad |= (((w3 ^ (w3 >> 16)) & 1u) | ((w3 & 1u) ^ gr));
            }
        }
        if (++guard > (1 << 14)) break;   // failsafe: wrong answer beats a hang
      }
      asm volatile("" ::: "memory");

      // ---- h-part MFMA (hfr delivered by the successful poll iteration)
#pragma unroll
      for (int kk = 0; kk < 4; ++kk)
#pragma unroll
        for (int n = 0; n < 4; ++n) {
          acc[0][n] = mfma_bf16(hfr[0][kk], bw[1][n][kk], acc[0][n]);
          acc[1][n] = mfma_bf16(hfr[1][kk], bw[1][n][kk], acc[1][n]);
        }
    }

    // MFMA->VALU/DS hazard guard (inline-asm MFMA bypasses hazard recognizer)
    asm volatile("s_nop 7\n\ts_nop 7" ::: "memory");

    // ---- per-wave partials; D layout: col=lane&15, row=(lane>>4)*4+reg
#pragma unroll
    for (int r = 0; r < 2; ++r)
#pragma unroll
      for (int n = 0; n < 4; ++n)
        *(vfloat4*)&red[wv][r][n][mrow][g4 * 4] = acc[r][n];
    __syncthreads();                                     // sync 1

    // ---- reduce across waves + bias
    float gate[4][2];
#pragma unroll
    for (int n = 0; n < 4; ++n) {
      float s0 = bsum[n][0], s1 = bsum[n][1];
#pragma unroll
      for (int w2 = 0; w2 < 4; ++w2) {
        s0 += red[w2][ort][n][om][odr];
        s1 += red[w2][ort][n][om + 1][odr];
      }
      gate[n][0] = s0; gate[n][1] = s1;
    }
    __syncthreads();   // sync 2: red reads complete before next-iter red writes

    // ---- activations, state update
    float hv[2];
#pragma unroll
    for (int e = 0; e < 2; ++e) {
      const float ig = sigmoid_(gate[0][e]);
      const float fg = sigmoid_(gate[1][e]);
      const float gg = tanh_(gate[2][e]);
      const float og = sigmoid_(gate[3][e]);
      cst[e] = fg * cst[e] + ig * gg;
      hv[e]  = og * tanh_(cst[e]);
    }
    hlast[0] = hv[0]; hlast[1] = hv[1];

    // ---- publish h with generation tag in each bf16 LSB (<=1 ulp distortion)
    {
      const unsigned gw = (((unsigned)t >> 1) & 1u) ^ 1u;
      unsigned u0 = f2bf(hv[0]);  u0 += ((u0 & 1u) ^ gw);
      unsigned u1 = f2bf(hv[1]);  u1 += ((u1 & 1u) ^ gw);
      const unsigned packed = (u0 & 0xffffu) | (u1 << 16);
      unsigned int* hbW = (unsigned int*)(hbuf +
          ((size_t)(t & 1) * BATCH + bg * 32) * 512 + orow * 512 + cg * 16 + om);
      __hip_atomic_store(hbW, packed, __ATOMIC_RELAXED, __HIP_MEMORY_SCOPE_AGENT);

      float2 h2; h2.x = hv[0]; h2.y = hv[1];
      *(float2*)&out[((size_t)t * BATCH + bg * 32 + orow) * 512 + cg * 16 + om] = h2;
    }

    // ---- stage x_{t+1} (wave-local slice); overlaps peers' publish latency
    if (t + 1 < T_STEPS) {
#pragma unroll
      for (int it = 0; it < 16; ++it) {
        const int idx = it * 64 + lane;
        const int row = idx >> 5;
        const int c4  = idx & 31;
        const int col = wv * 128 + c4 * 4;
        const float4 v = *(const float4*)(word_seq +
            ((size_t)(t + 1) * BATCH + bg * 32 + row) * 512 + col);
        ushort4 us;
        us.x = f2bf(v.x); us.y = f2bf(v.y); us.z = f2bf(v.z); us.w = f2bf(v.w);
        *(ushort4*)&x_s[row][col] = us;
      }
    }
  }

  // ------- tails: final h and c (fp32) -------
  {
    const size_t tail = (size_t)T_STEPS * BATCH * HDIM;
    const size_t gb   = (size_t)bg * 32 + orow;
    const int    col  = cg * 16 + om;
    float2 h2; h2.x = hlast[0]; h2.y = hlast[1];
    float2 c2; c2.x = cst[0];   c2.y = cst[1];
    *(float2*)&out[tail + gb * 512 + col] = h2;
    *(float2*)&out[tail + (size_t)BATCH * HDIM + gb * 512 + col] = c2;
  }
}

extern "C" void kernel_launch(void* const* d_in, const int* in_sizes, int n_in,
                              void* d_out, int out_size, void* d_ws, size_t ws_size,
                              hipStream_t stream) {
  (void)in_sizes; (void)n_in; (void)out_size; (void)ws_size;
  const float* word_seq = (const float*)d_in[0];
  const float* w_ih     = (const float*)d_in[1];
  const float* w_hh     = (const float*)d_in[2];
  const float* b_ih     = (const float*)d_in[3];
  const float* b_hh     = (const float*)d_in[4];
  float* out = (float*)d_out;

  unsigned short* hbuf = (unsigned short*)((char*)d_ws + 8192);

  lstm_zero_ws<<<136, 256, 0, stream>>>((unsigned int*)d_ws);
  lstm_persistent<<<64, 320, 0, stream>>>(word_seq, w_ih, w_hh, b_ih, b_hh,
                                          out, hbuf);
}